// Round 13
// baseline (166.132 us; speedup 1.0000x reference)
//
#include <hip/hip_runtime.h>

#define B_ 8
#define LQ 512
#define LK 512
#define HDIM 1024
#define NH_ 16
#define HD_ 64

typedef unsigned short u16;
typedef unsigned char u8;
typedef unsigned long long u64;
typedef __attribute__((ext_vector_type(4))) float f32x4;
typedef __attribute__((ext_vector_type(4))) int i32x4;
typedef __attribute__((ext_vector_type(8))) __bf16 bf16x8;

static __device__ __forceinline__ u16 f2bf(float f) {
    union { float f; unsigned u; } v; v.f = f;
    unsigned u = v.u;
    return (u16)((u + 0x7fffu + ((u >> 16) & 1u)) >> 16);
}

static __device__ __forceinline__ float bf2f(u16 u) {
    union { unsigned u; float f; } v; v.u = ((unsigned)u) << 16;
    return v.f;
}

static __device__ __forceinline__ void gload_lds16(const u16* g, u16* l) {
    __builtin_amdgcn_global_load_lds((const __attribute__((address_space(1))) unsigned*)g,
                                     (__attribute__((address_space(3))) unsigned*)l, 16, 0, 0);
}

// ---- K1: weight transpose + cast: WT[n][k] = bf16(W[k][n]) ----
__global__ void wcast_kernel(const float* __restrict__ w0, const float* __restrict__ w1,
                             const float* __restrict__ w2, const float* __restrict__ w3,
                             u16* __restrict__ o0, u16* __restrict__ o1,
                             u16* __restrict__ o2, u16* __restrict__ o3) {
    const float* W; u16* O;
    switch (blockIdx.z) { case 0: W = w0; O = o0; break; case 1: W = w1; O = o1; break;
                          case 2: W = w2; O = o2; break; default: W = w3; O = o3; }
    __shared__ float t[32][33];
    int tx = threadIdx.x, ty = threadIdx.y;
    int n0 = blockIdx.x * 32, k0 = blockIdx.y * 32;
#pragma unroll
    for (int i = 0; i < 4; i++) {
        int k = ty * 4 + i;
        t[k][tx] = W[(k0 + k) * HDIM + n0 + tx];
    }
    __syncthreads();
#pragma unroll
    for (int i = 0; i < 4; i++) {
        int n = ty * 4 + i;
        O[(n0 + n) * HDIM + k0 + tx] = f2bf(t[tx][n]);
    }
}

// ---- K2: projection GEMM; A staged DIRECTLY from f32 global (no xcast) ----
__global__ __launch_bounds__(256) void proj3_kernel(
    const float* __restrict__ x0, const float* __restrict__ x1, const float* __restrict__ x2,
    const u16* __restrict__ wt0, const u16* __restrict__ wt1, const u16* __restrict__ wt2,
    const float* __restrict__ bi0, const float* __restrict__ bi1, const float* __restrict__ bi2,
    u16* __restrict__ ot0, u16* __restrict__ ot1, u16* __restrict__ ot2)
{
    __shared__ u16 As[128 * 64];
    __shared__ u16 Bs[128 * 64];
    int bid = blockIdx.x;
    int swz = (bid & 7) * 96 + (bid >> 3);
    int z = swz >> 8, rem = swz & 255;
    int Mb = (rem >> 3) * 128, Nb = (rem & 7) * 128;
    const float* X; const u16* WT; const float* bias; u16* out;
    switch (z) {
        case 0: X = x0; WT = wt0; bias = bi0; out = ot0; break;
        case 1: X = x1; WT = wt1; bias = bi1; out = ot1; break;
        default: X = x2; WT = wt2; bias = bi2; out = ot2; break;
    }
    int tid = threadIdx.x, lane = tid & 63, w = tid >> 6;
    int wm = (w & 1) * 64, wn = (w >> 1) * 64;
    int r16 = lane & 15, kg = lane >> 4;
    int rsw = (r16 & 7) * 8;
    int srow = lane >> 3;
    int scol = 8 * ((lane & 7) ^ (lane >> 3));
    const float* gA = X + (size_t)Mb * HDIM;
    const u16* gB = WT + (size_t)Nb * HDIM;

    f32x4 acc[4][4] = {};
    for (int k0 = 0; k0 < HDIM; k0 += 64) {
        // A: f32 global -> regs -> bf16 -> swizzled LDS (same layout gload path produced:
        // granule g holds source col-group (g&7)^(row&7))
#pragma unroll
        for (int i = 0; i < 4; i++) {
            int g = tid + i * 256;
            int row = g >> 3, gl = g & 7;
            int cg = ((gl ^ (row & 7)) * 8);
            const float* src = &gA[(size_t)row * HDIM + k0 + cg];
            f32x4 v0 = *(const f32x4*)src;
            f32x4 v1 = *(const f32x4*)(src + 4);
            union { u16 u[8]; i32x4 vv; } p;
            p.u[0] = f2bf(v0[0]); p.u[1] = f2bf(v0[1]); p.u[2] = f2bf(v0[2]); p.u[3] = f2bf(v0[3]);
            p.u[4] = f2bf(v1[0]); p.u[5] = f2bf(v1[1]); p.u[6] = f2bf(v1[2]); p.u[7] = f2bf(v1[3]);
            *(i32x4*)&As[g * 8] = p.vv;
        }
        // B: bf16 via global_load_lds (unchanged)
#pragma unroll
        for (int i = 0; i < 4; i++) {
            int c = w * 4 + i;
            int row = c * 8 + srow;
            gload_lds16(&gB[(size_t)row * HDIM + k0 + scol], &Bs[c * 512]);
        }
        __syncthreads();
#pragma unroll
        for (int kk = 0; kk < 2; kk++) {
            int colp = (kk * 32 + kg * 8) ^ rsw;
            bf16x8 a[4], b[4];
#pragma unroll
            for (int mt = 0; mt < 4; mt++) a[mt] = *(const bf16x8*)&As[(wm + mt * 16 + r16) * 64 + colp];
#pragma unroll
            for (int nt = 0; nt < 4; nt++) b[nt] = *(const bf16x8*)&Bs[(wn + nt * 16 + r16) * 64 + colp];
#pragma unroll
            for (int mt = 0; mt < 4; mt++)
#pragma unroll
                for (int nt = 0; nt < 4; nt++)
                    acc[mt][nt] = __builtin_amdgcn_mfma_f32_16x16x32_bf16(a[mt], b[nt], acc[mt][nt], 0, 0, 0);
        }
        __syncthreads();
    }
    int cr = (lane >> 4) * 4, cc = lane & 15;
#pragma unroll
    for (int nt = 0; nt < 4; nt++) {
        int n = Nb + wn + nt * 16 + cc;
        float bv = bias[n];
        int h = n >> 6, d = n & 63;
#pragma unroll
        for (int mt = 0; mt < 4; mt++) {
#pragma unroll
            for (int j = 0; j < 4; j++) {
                int m = Mb + wm + mt * 16 + cr + j;
                int b = m >> 9, l = m & 511;
                out[(((b * NH_ + h) * LQ) + l) * HD_ + d] = f2bf(acc[mt][nt][j] + bv);
            }
        }
    }
}

// ---- K2b: merged mid = vtrans (blocks 0..4095) + biasprep (blocks 4096..6143) ----
__global__ __launch_bounds__(256) void mid_kernel(
    const u16* __restrict__ vb, u16* __restrict__ vT,
    const float* __restrict__ rel_table, const float* __restrict__ local_bias,
    const float* __restrict__ log_scale, const float* __restrict__ att_bias,
    u16* __restrict__ Tb)
{
    __shared__ u16 t[32][33];
    int bid = blockIdx.x, tid = threadIdx.x;
    if (bid < 4096) {
        int kx = bid & 15, dy = (bid >> 4) & 1, bh = bid >> 5;
        int k0 = kx * 32, d0 = dy * 32;
        int tx = tid & 31, ty = tid >> 5;
        const u16* src = vb + (size_t)bh * (LK * HD_);
        u16* dst = vT + (size_t)bh * (LK * HD_);
#pragma unroll
        for (int i = 0; i < 4; i++) {
            int k = ty * 4 + i;
            t[k][tx] = src[(k0 + k) * HD_ + d0 + tx];
        }
        __syncthreads();
#pragma unroll
        for (int i = 0; i < 4; i++) {
            int d = ty * 4 + i;
            dst[(d0 + d) * LK + k0 + tx] = t[tx][d];
        }
    } else {
        int idx = (bid - 4096) * 256 + tid;
        int base = idx * 8;
        int h = base >> 18;
        int rem = base & 262143;
        int qi = rem >> 9, ki0 = rem & 511;
        float scale = fminf(fmaxf(__expf(log_scale[0]), 1.0f), 4.0f);
        float ab = att_bias[0];
        union { u16 u[8]; i32x4 v; } o;
#pragma unroll
        for (int tt = 0; tt < 8; tt++) {
            int ki = ki0 + tt;
            float r = rel_table[(qi - ki + 511) * NH_ + h];
            float lb = local_bias[qi * 512 + ki];
            o.u[tt] = f2bf((r + lb * 0.05f) * scale + ab);
        }
        *(i32x4*)&Tb[base] = o.v;
    }
}

// ---- K3: fused scores + softmax + attn write + PV (R12 attn2, verbatim) ----
__global__ __launch_bounds__(512) void attn2_kernel(
    const u16* __restrict__ qb, const u16* __restrict__ kb, const u16* __restrict__ vT,
    const int* __restrict__ kpm, const u16* __restrict__ Tb,
    const float* __restrict__ log_scale,
    float* __restrict__ attn_out, u16* __restrict__ ctx)
{
    __shared__ u16 Qs[32][72];
    __shared__ u8 pmask[512];
    __shared__ float red[2][32][8];
    __shared__ u16 P[32][520];
    __shared__ float pred[4][32][16];

    int bh = blockIdx.y;
    int q0 = blockIdx.x * 32;
    int b = bh >> 4, h = bh & 15;
    int tid = threadIdx.x, lane = tid & 63, w = tid >> 6;
    int r16 = lane & 15, kg = lane >> 4;

    float cscale = 0.125f * fminf(fmaxf(__expf(log_scale[0]), 1.0f), 4.0f);

    if (tid < 256) {
        int row = tid >> 3, c8 = tid & 7;
        *(i32x4*)&Qs[row][c8 * 8] = *(const i32x4*)&qb[((size_t)bh * LQ + q0 + row) * HD_ + c8 * 8];
    }
    pmask[tid & 511] = (u8)(kpm[b * LK + (tid & 511)] != 0);
    __syncthreads();

    bf16x8 aq[2][2];
#pragma unroll
    for (int m = 0; m < 2; m++)
#pragma unroll
        for (int kk = 0; kk < 2; kk++)
            aq[m][kk] = *(const bf16x8*)&Qs[m * 16 + r16][kk * 32 + kg * 8];

    f32x4 acc[2][4] = {};
    const u16* kbase = kb + ((size_t)bh * LK + w * 64) * HD_;
#pragma unroll
    for (int nt = 0; nt < 4; nt++) {
        bf16x8 bk0 = *(const bf16x8*)&kbase[(nt * 16 + r16) * HD_ + kg * 8];
        bf16x8 bk1 = *(const bf16x8*)&kbase[(nt * 16 + r16) * HD_ + 32 + kg * 8];
#pragma unroll
        for (int m = 0; m < 2; m++) {
            acc[m][nt] = __builtin_amdgcn_mfma_f32_16x16x32_bf16(aq[m][0], bk0, acc[m][nt], 0, 0, 0);
            acc[m][nt] = __builtin_amdgcn_mfma_f32_16x16x32_bf16(aq[m][1], bk1, acc[m][nt], 0, 0, 0);
        }
    }

    const u16* Th = Tb + ((size_t)h << 18);
    float rm[2][4];
#pragma unroll
    for (int m = 0; m < 2; m++)
#pragma unroll
        for (int j = 0; j < 4; j++) rm[m][j] = -1e30f;
#pragma unroll
    for (int m = 0; m < 2; m++) {
#pragma unroll
        for (int nt = 0; nt < 4; nt++) {
            int ki = w * 64 + nt * 16 + r16;
            bool masked = (pmask[ki] == 0);
#pragma unroll
            for (int j = 0; j < 4; j++) {
                int row = m * 16 + kg * 4 + j;
                int qi = q0 + row;
                float s = fmaf(acc[m][nt][j], cscale, bf2f(Th[qi * 512 + ki]));
                s = fminf(fmaxf(s, -50.0f), 50.0f);
                s = masked ? -50.0f : s;
                acc[m][nt][j] = s;
                rm[m][j] = fmaxf(rm[m][j], s);
            }
        }
    }
#pragma unroll
    for (int m = 0; m < 2; m++)
#pragma unroll
        for (int j = 0; j < 4; j++) {
            float v = rm[m][j];
            v = fmaxf(v, __shfl_xor(v, 1));
            v = fmaxf(v, __shfl_xor(v, 2));
            v = fmaxf(v, __shfl_xor(v, 4));
            v = fmaxf(v, __shfl_xor(v, 8));
            rm[m][j] = v;
        }
    if (r16 == 0) {
#pragma unroll
        for (int m = 0; m < 2; m++)
#pragma unroll
            for (int j = 0; j < 4; j++) red[0][m * 16 + kg * 4 + j][w] = rm[m][j];
    }
    __syncthreads();
    float fm[2][4];
#pragma unroll
    for (int m = 0; m < 2; m++)
#pragma unroll
        for (int j = 0; j < 4; j++) {
            int row = m * 16 + kg * 4 + j;
            float v = red[0][row][0];
#pragma unroll
            for (int ww = 1; ww < 8; ww++) v = fmaxf(v, red[0][row][ww]);
            fm[m][j] = v;
        }
    float ps[2][4] = {};
#pragma unroll
    for (int m = 0; m < 2; m++)
#pragma unroll
        for (int nt = 0; nt < 4; nt++)
#pragma unroll
            for (int j = 0; j < 4; j++) {
                float e = __expf(acc[m][nt][j] - fm[m][j]);
                acc[m][nt][j] = e;
                ps[m][j] += e;
            }
#pragma unroll
    for (int m = 0; m < 2; m++)
#pragma unroll
        for (int j = 0; j < 4; j++) {
            float v = ps[m][j];
            v += __shfl_xor(v, 1);
            v += __shfl_xor(v, 2);
            v += __shfl_xor(v, 4);
            v += __shfl_xor(v, 8);
            ps[m][j] = v;
        }
    if (r16 == 0) {
#pragma unroll
        for (int m = 0; m < 2; m++)
#pragma unroll
            for (int j = 0; j < 4; j++) red[1][m * 16 + kg * 4 + j][w] = ps[m][j];
    }
    __syncthreads();

    float* dst = attn_out + ((size_t)bh * LQ + q0) * (size_t)LK + w * 64;
#pragma unroll
    for (int m = 0; m < 2; m++)
#pragma unroll
        for (int j = 0; j < 4; j++) {
            int row = m * 16 + kg * 4 + j;
            float sum = 0.f;
#pragma unroll
            for (int ww = 0; ww < 8; ww++) sum += red[1][row][ww];
            float inv = 1.0f / sum;
#pragma unroll
            for (int nt = 0; nt < 4; nt++) {
                float p = acc[m][nt][j] * inv;
                __builtin_nontemporal_store(p, &dst[(size_t)row * LK + nt * 16 + r16]);
                P[row][w * 64 + nt * 16 + r16] = f2bf(p);
            }
        }
    __syncthreads();

    int wd = (w & 3) * 16;
    int kh = (w >> 2) * 256;
    const u16* vbase = vT + (size_t)bh * (HD_ * LK);
    f32x4 po[2] = {};
#pragma unroll
    for (int kt = 0; kt < 8; kt++) {
        int k0 = kh + kt * 32;
        bf16x8 bvf = *(const bf16x8*)&vbase[(size_t)(wd + r16) * LK + k0 + kg * 8];
#pragma unroll
        for (int m = 0; m < 2; m++) {
            bf16x8 af = *(const bf16x8*)&P[m * 16 + r16][k0 + kg * 8];
            po[m] = __builtin_amdgcn_mfma_f32_16x16x32_bf16(af, bvf, po[m], 0, 0, 0);
        }
    }
    if (w >= 4) {
#pragma unroll
        for (int m = 0; m < 2; m++)
#pragma unroll
            for (int j = 0; j < 4; j++)
                pred[w & 3][m * 16 + kg * 4 + j][r16] = po[m][j];
    }
    __syncthreads();
    if (w < 4) {
#pragma unroll
        for (int m = 0; m < 2; m++)
#pragma unroll
            for (int j = 0; j < 4; j++) {
                int row = m * 16 + kg * 4 + j;
                float v = po[m][j] + pred[w][row][r16];
                ctx[((size_t)(b * LQ + q0 + row)) * HDIM + h * HD_ + wd + r16] = f2bf(v);
            }
    }
}

// ---- K4: output projection (bf16 gemm_bt, m97 structure, f32 out) ----
__global__ __launch_bounds__(256) void oproj2_kernel(
    const u16* __restrict__ ctx, const u16* __restrict__ WT,
    const float* __restrict__ bias, float* __restrict__ out)
{
    __shared__ u16 As[128 * 64];
    __shared__ u16 Bs[128 * 64];
    int bid = blockIdx.x;
    int idx = (bid & 7) * 32 + (bid >> 3);
    int Mb = (idx >> 3) * 128, Nb = (idx & 7) * 128;
    int tid = threadIdx.x, lane = tid & 63, w = tid >> 6;
    int wm = (w & 1) * 64, wn = (w >> 1) * 64;
    int r16 = lane & 15, kg = lane >> 4;
    int rsw = (r16 & 7) * 8;
    int srow = lane >> 3;
    int scol = 8 * ((lane & 7) ^ (lane >> 3));
    const u16* gA = ctx + (size_t)Mb * HDIM;
    const u16* gB = WT + (size_t)Nb * HDIM;

    f32x4 acc[4][4] = {};
    for (int k0 = 0; k0 < HDIM; k0 += 64) {
#pragma unroll
        for (int i = 0; i < 4; i++) {
            int c = w * 4 + i;
            int row = c * 8 + srow;
            gload_lds16(&gA[(size_t)row * HDIM + k0 + scol], &As[c * 512]);
            gload_lds16(&gB[(size_t)row * HDIM + k0 + scol], &Bs[c * 512]);
        }
        __syncthreads();
#pragma unroll
        for (int kk = 0; kk < 2; kk++) {
            int colp = (kk * 32 + kg * 8) ^ rsw;
            bf16x8 a[4], b[4];
#pragma unroll
            for (int mt = 0; mt < 4; mt++) a[mt] = *(const bf16x8*)&As[(wm + mt * 16 + r16) * 64 + colp];
#pragma unroll
            for (int nt = 0; nt < 4; nt++) b[nt] = *(const bf16x8*)&Bs[(wn + nt * 16 + r16) * 64 + colp];
#pragma unroll
            for (int mt = 0; mt < 4; mt++)
#pragma unroll
                for (int nt = 0; nt < 4; nt++)
                    acc[mt][nt] = __builtin_amdgcn_mfma_f32_16x16x32_bf16(a[mt], b[nt], acc[mt][nt], 0, 0, 0);
        }
        __syncthreads();
    }
    int cr = (lane >> 4) * 4, cc = lane & 15;
#pragma unroll
    for (int nt = 0; nt < 4; nt++) {
        int n = Nb + wn + nt * 16 + cc;
        float bv = bias[n];
#pragma unroll
        for (int mt = 0; mt < 4; mt++) {
#pragma unroll
            for (int j = 0; j < 4; j++) {
                int m = Mb + wm + mt * 16 + cr + j;
                out[(size_t)m * HDIM + n] = acc[mt][nt][j] + bv;
            }
        }
    }
}

extern "C" void kernel_launch(void* const* d_in, const int* in_sizes, int n_in,
                              void* d_out, int out_size, void* d_ws, size_t ws_size,
                              hipStream_t stream) {
    (void)in_sizes; (void)n_in; (void)out_size; (void)ws_size;
    const float* query = (const float*)d_in[0];
    const float* key_  = (const float*)d_in[1];
    const float* value = (const float*)d_in[2];
    const int*   kpm   = (const int*)d_in[3];
    const float* Wq = (const float*)d_in[4];  const float* bq = (const float*)d_in[5];
    const float* Wk = (const float*)d_in[6];  const float* bk = (const float*)d_in[7];
    const float* Wv = (const float*)d_in[8];  const float* bv = (const float*)d_in[9];
    const float* Wo = (const float*)d_in[10]; const float* bo = (const float*)d_in[11];
    const float* rel_table  = (const float*)d_in[12];
    const float* local_bias = (const float*)d_in[13];
    const float* log_scale  = (const float*)d_in[14];
    const float* att_bias   = (const float*)d_in[15];

    char* ws = (char*)d_ws;
    u16* WTq = (u16*)(ws + 0ull);
    u16* WTk = (u16*)(ws + (2ull << 20));
    u16* WTv = (u16*)(ws + (4ull << 20));
    u16* WTo = (u16*)(ws + (6ull << 20));
    u16* qb  = (u16*)(ws + (8ull << 20));
    u16* kb  = (u16*)(ws + (16ull << 20));
    u16* vb  = (u16*)(ws + (24ull << 20));
    u16* vT  = (u16*)(ws + (32ull << 20));
    u16* ctx = (u16*)(ws + (40ull << 20));
    u16* Tb  = (u16*)(ws + (48ull << 20));

    float* out  = (float*)d_out;
    float* attn = out + (size_t)4096 * 1024;

    wcast_kernel<<<dim3(32, 32, 4), dim3(32, 8), 0, stream>>>(Wq, Wk, Wv, Wo, WTq, WTk, WTv, WTo);
    proj3_kernel<<<768, 256, 0, stream>>>(query, key_, value, WTq, WTk, WTv, bq, bk, bv, qb, kb, vb);
    mid_kernel<<<6144, 256, 0, stream>>>(vb, vT, rel_table, local_bias, log_scale, att_bias, Tb);
    attn2_kernel<<<dim3(16, 128), 512, 0, stream>>>(qb, kb, vT, kpm, Tb, log_scale, attn, ctx);
    oproj2_kernel<<<256, 256, 0, stream>>>(ctx, WTo, bo, out);
}

// Round 14
// 161.505 us; speedup vs baseline: 1.0287x; 1.0287x over previous
//
#include <hip/hip_runtime.h>

#define B_ 8
#define LQ 512
#define LK 512
#define HDIM 1024
#define NH_ 16
#define HD_ 64

typedef unsigned short u16;
typedef unsigned char u8;
typedef unsigned long long u64;
typedef __attribute__((ext_vector_type(4))) float f32x4;
typedef __attribute__((ext_vector_type(4))) int i32x4;
typedef __attribute__((ext_vector_type(8))) __bf16 bf16x8;

static __device__ __forceinline__ u16 f2bf(float f) {
    union { float f; unsigned u; } v; v.f = f;
    unsigned u = v.u;
    return (u16)((u + 0x7fffu + ((u >> 16) & 1u)) >> 16);
}

static __device__ __forceinline__ float bf2f(u16 u) {
    union { unsigned u; float f; } v; v.u = ((unsigned)u) << 16;
    return v.f;
}

static __device__ __forceinline__ void gload_lds16(const u16* g, u16* l) {
    __builtin_amdgcn_global_load_lds((const __attribute__((address_space(1))) unsigned*)g,
                                     (__attribute__((address_space(3))) unsigned*)l, 16, 0, 0);
}

// ---- K0: merged prep1 = xcast (blocks 0..12287) + wcast (blocks 12288..16383) ----
__global__ __launch_bounds__(256) void prep1_kernel(
    const float* __restrict__ q, const float* __restrict__ k, const float* __restrict__ v,
    u16* __restrict__ xq, u16* __restrict__ xk, u16* __restrict__ xv,
    const float* __restrict__ w0, const float* __restrict__ w1,
    const float* __restrict__ w2, const float* __restrict__ w3,
    u16* __restrict__ o0, u16* __restrict__ o1,
    u16* __restrict__ o2, u16* __restrict__ o3)
{
    __shared__ float t[32][33];
    int bid = blockIdx.x, tid = threadIdx.x;
    if (bid < 12288) {
        int z = bid >> 12, blk = bid & 4095;
        const float* X = (z == 0) ? q : (z == 1) ? k : v;
        u16* O = (z == 0) ? xq : (z == 1) ? xk : xv;
        int i = blk * 256 + tid;
        f32x4 vv = ((const f32x4*)X)[i];
        union { u16 u[4]; u64 ull; } p;
        p.u[0] = f2bf(vv[0]); p.u[1] = f2bf(vv[1]); p.u[2] = f2bf(vv[2]); p.u[3] = f2bf(vv[3]);
        ((u64*)O)[i] = p.ull;
    } else {
        int r = bid - 12288;
        int z = r >> 10, blk = r & 1023;
        const float* W; u16* O;
        switch (z) { case 0: W = w0; O = o0; break; case 1: W = w1; O = o1; break;
                     case 2: W = w2; O = o2; break; default: W = w3; O = o3; }
        int tx = tid & 31, ty = tid >> 5;
        int n0 = (blk & 31) * 32, k0 = (blk >> 5) * 32;
#pragma unroll
        for (int i = 0; i < 4; i++) {
            int kk = ty * 4 + i;
            t[kk][tx] = W[(k0 + kk) * HDIM + n0 + tx];
        }
        __syncthreads();
#pragma unroll
        for (int i = 0; i < 4; i++) {
            int n = ty * 4 + i;
            O[(n0 + n) * HDIM + k0 + tx] = f2bf(t[tx][n]);
        }
    }
}

// ---- K2: projection GEMM (bf16, m97 structure) ----
__global__ __launch_bounds__(256) void proj2_kernel(
    const u16* __restrict__ x0, const u16* __restrict__ x1, const u16* __restrict__ x2,
    const u16* __restrict__ wt0, const u16* __restrict__ wt1, const u16* __restrict__ wt2,
    const float* __restrict__ bi0, const float* __restrict__ bi1, const float* __restrict__ bi2,
    u16* __restrict__ ot0, u16* __restrict__ ot1, u16* __restrict__ ot2)
{
    __shared__ u16 As[128 * 64];
    __shared__ u16 Bs[128 * 64];
    int bid = blockIdx.x;
    int swz = (bid & 7) * 96 + (bid >> 3);
    int z = swz >> 8, rem = swz & 255;
    int Mb = (rem >> 3) * 128, Nb = (rem & 7) * 128;
    const u16* X; const u16* WT; const float* bias; u16* out;
    switch (z) {
        case 0: X = x0; WT = wt0; bias = bi0; out = ot0; break;
        case 1: X = x1; WT = wt1; bias = bi1; out = ot1; break;
        default: X = x2; WT = wt2; bias = bi2; out = ot2; break;
    }
    int tid = threadIdx.x, lane = tid & 63, w = tid >> 6;
    int wm = (w & 1) * 64, wn = (w >> 1) * 64;
    int r16 = lane & 15, kg = lane >> 4;
    int rsw = (r16 & 7) * 8;
    int srow = lane >> 3;
    int scol = 8 * ((lane & 7) ^ (lane >> 3));
    const u16* gA = X + (size_t)Mb * HDIM;
    const u16* gB = WT + (size_t)Nb * HDIM;

    f32x4 acc[4][4] = {};
    for (int k0 = 0; k0 < HDIM; k0 += 64) {
#pragma unroll
        for (int i = 0; i < 4; i++) {
            int c = w * 4 + i;
            int row = c * 8 + srow;
            gload_lds16(&gA[(size_t)row * HDIM + k0 + scol], &As[c * 512]);
            gload_lds16(&gB[(size_t)row * HDIM + k0 + scol], &Bs[c * 512]);
        }
        __syncthreads();
#pragma unroll
        for (int kk = 0; kk < 2; kk++) {
            int colp = (kk * 32 + kg * 8) ^ rsw;
            bf16x8 a[4], b[4];
#pragma unroll
            for (int mt = 0; mt < 4; mt++) a[mt] = *(const bf16x8*)&As[(wm + mt * 16 + r16) * 64 + colp];
#pragma unroll
            for (int nt = 0; nt < 4; nt++) b[nt] = *(const bf16x8*)&Bs[(wn + nt * 16 + r16) * 64 + colp];
#pragma unroll
            for (int mt = 0; mt < 4; mt++)
#pragma unroll
                for (int nt = 0; nt < 4; nt++)
                    acc[mt][nt] = __builtin_amdgcn_mfma_f32_16x16x32_bf16(a[mt], b[nt], acc[mt][nt], 0, 0, 0);
        }
        __syncthreads();
    }
    int cr = (lane >> 4) * 4, cc = lane & 15;
#pragma unroll
    for (int nt = 0; nt < 4; nt++) {
        int n = Nb + wn + nt * 16 + cc;
        float bv = bias[n];
        int h = n >> 6, d = n & 63;
#pragma unroll
        for (int mt = 0; mt < 4; mt++) {
#pragma unroll
            for (int j = 0; j < 4; j++) {
                int m = Mb + wm + mt * 16 + cr + j;
                int b = m >> 9, l = m & 511;
                out[(((b * NH_ + h) * LQ) + l) * HD_ + d] = f2bf(acc[mt][nt][j] + bv);
            }
        }
    }
}

// ---- K2b: merged mid = vtrans (blocks 0..4095) + biasprep (blocks 4096..6143) ----
__global__ __launch_bounds__(256) void mid_kernel(
    const u16* __restrict__ vb, u16* __restrict__ vT,
    const float* __restrict__ rel_table, const float* __restrict__ local_bias,
    const float* __restrict__ log_scale, const float* __restrict__ att_bias,
    u16* __restrict__ Tb)
{
    __shared__ u16 t[32][33];
    int bid = blockIdx.x, tid = threadIdx.x;
    if (bid < 4096) {
        int kx = bid & 15, dy = (bid >> 4) & 1, bh = bid >> 5;
        int k0 = kx * 32, d0 = dy * 32;
        int tx = tid & 31, ty = tid >> 5;
        const u16* src = vb + (size_t)bh * (LK * HD_);
        u16* dst = vT + (size_t)bh * (LK * HD_);
#pragma unroll
        for (int i = 0; i < 4; i++) {
            int k = ty * 4 + i;
            t[k][tx] = src[(k0 + k) * HD_ + d0 + tx];
        }
        __syncthreads();
#pragma unroll
        for (int i = 0; i < 4; i++) {
            int d = ty * 4 + i;
            dst[(d0 + d) * LK + k0 + tx] = t[tx][d];
        }
    } else {
        int idx = (bid - 4096) * 256 + tid;
        int base = idx * 8;
        int h = base >> 18;
        int rem = base & 262143;
        int qi = rem >> 9, ki0 = rem & 511;
        float scale = fminf(fmaxf(__expf(log_scale[0]), 1.0f), 4.0f);
        float ab = att_bias[0];
        union { u16 u[8]; i32x4 v; } o;
#pragma unroll
        for (int tt = 0; tt < 8; tt++) {
            int ki = ki0 + tt;
            float r = rel_table[(qi - ki + 511) * NH_ + h];
            float lb = local_bias[qi * 512 + ki];
            o.u[tt] = f2bf((r + lb * 0.05f) * scale + ab);
        }
        *(i32x4*)&Tb[base] = o.v;
    }
}

// ---- K3: fused scores + softmax + attn write + PV (R12 attn2, verbatim) ----
__global__ __launch_bounds__(512) void attn2_kernel(
    const u16* __restrict__ qb, const u16* __restrict__ kb, const u16* __restrict__ vT,
    const int* __restrict__ kpm, const u16* __restrict__ Tb,
    const float* __restrict__ log_scale,
    float* __restrict__ attn_out, u16* __restrict__ ctx)
{
    __shared__ u16 Qs[32][72];
    __shared__ u8 pmask[512];
    __shared__ float red[2][32][8];
    __shared__ u16 P[32][520];
    __shared__ float pred[4][32][16];

    int bh = blockIdx.y;
    int q0 = blockIdx.x * 32;
    int b = bh >> 4, h = bh & 15;
    int tid = threadIdx.x, lane = tid & 63, w = tid >> 6;
    int r16 = lane & 15, kg = lane >> 4;

    float cscale = 0.125f * fminf(fmaxf(__expf(log_scale[0]), 1.0f), 4.0f);

    if (tid < 256) {
        int row = tid >> 3, c8 = tid & 7;
        *(i32x4*)&Qs[row][c8 * 8] = *(const i32x4*)&qb[((size_t)bh * LQ + q0 + row) * HD_ + c8 * 8];
    }
    pmask[tid & 511] = (u8)(kpm[b * LK + (tid & 511)] != 0);
    __syncthreads();

    bf16x8 aq[2][2];
#pragma unroll
    for (int m = 0; m < 2; m++)
#pragma unroll
        for (int kk = 0; kk < 2; kk++)
            aq[m][kk] = *(const bf16x8*)&Qs[m * 16 + r16][kk * 32 + kg * 8];

    f32x4 acc[2][4] = {};
    const u16* kbase = kb + ((size_t)bh * LK + w * 64) * HD_;
#pragma unroll
    for (int nt = 0; nt < 4; nt++) {
        bf16x8 bk0 = *(const bf16x8*)&kbase[(nt * 16 + r16) * HD_ + kg * 8];
        bf16x8 bk1 = *(const bf16x8*)&kbase[(nt * 16 + r16) * HD_ + 32 + kg * 8];
#pragma unroll
        for (int m = 0; m < 2; m++) {
            acc[m][nt] = __builtin_amdgcn_mfma_f32_16x16x32_bf16(aq[m][0], bk0, acc[m][nt], 0, 0, 0);
            acc[m][nt] = __builtin_amdgcn_mfma_f32_16x16x32_bf16(aq[m][1], bk1, acc[m][nt], 0, 0, 0);
        }
    }

    const u16* Th = Tb + ((size_t)h << 18);
    float rm[2][4];
#pragma unroll
    for (int m = 0; m < 2; m++)
#pragma unroll
        for (int j = 0; j < 4; j++) rm[m][j] = -1e30f;
#pragma unroll
    for (int m = 0; m < 2; m++) {
#pragma unroll
        for (int nt = 0; nt < 4; nt++) {
            int ki = w * 64 + nt * 16 + r16;
            bool masked = (pmask[ki] == 0);
#pragma unroll
            for (int j = 0; j < 4; j++) {
                int row = m * 16 + kg * 4 + j;
                int qi = q0 + row;
                float s = fmaf(acc[m][nt][j], cscale, bf2f(Th[qi * 512 + ki]));
                s = fminf(fmaxf(s, -50.0f), 50.0f);
                s = masked ? -50.0f : s;
                acc[m][nt][j] = s;
                rm[m][j] = fmaxf(rm[m][j], s);
            }
        }
    }
#pragma unroll
    for (int m = 0; m < 2; m++)
#pragma unroll
        for (int j = 0; j < 4; j++) {
            float v = rm[m][j];
            v = fmaxf(v, __shfl_xor(v, 1));
            v = fmaxf(v, __shfl_xor(v, 2));
            v = fmaxf(v, __shfl_xor(v, 4));
            v = fmaxf(v, __shfl_xor(v, 8));
            rm[m][j] = v;
        }
    if (r16 == 0) {
#pragma unroll
        for (int m = 0; m < 2; m++)
#pragma unroll
            for (int j = 0; j < 4; j++) red[0][m * 16 + kg * 4 + j][w] = rm[m][j];
    }
    __syncthreads();
    float fm[2][4];
#pragma unroll
    for (int m = 0; m < 2; m++)
#pragma unroll
        for (int j = 0; j < 4; j++) {
            int row = m * 16 + kg * 4 + j;
            float v = red[0][row][0];
#pragma unroll
            for (int ww = 1; ww < 8; ww++) v = fmaxf(v, red[0][row][ww]);
            fm[m][j] = v;
        }
    float ps[2][4] = {};
#pragma unroll
    for (int m = 0; m < 2; m++)
#pragma unroll
        for (int nt = 0; nt < 4; nt++)
#pragma unroll
            for (int j = 0; j < 4; j++) {
                float e = __expf(acc[m][nt][j] - fm[m][j]);
                acc[m][nt][j] = e;
                ps[m][j] += e;
            }
#pragma unroll
    for (int m = 0; m < 2; m++)
#pragma unroll
        for (int j = 0; j < 4; j++) {
            float v = ps[m][j];
            v += __shfl_xor(v, 1);
            v += __shfl_xor(v, 2);
            v += __shfl_xor(v, 4);
            v += __shfl_xor(v, 8);
            ps[m][j] = v;
        }
    if (r16 == 0) {
#pragma unroll
        for (int m = 0; m < 2; m++)
#pragma unroll
            for (int j = 0; j < 4; j++) red[1][m * 16 + kg * 4 + j][w] = ps[m][j];
    }
    __syncthreads();

    float* dst = attn_out + ((size_t)bh * LQ + q0) * (size_t)LK + w * 64;
#pragma unroll
    for (int m = 0; m < 2; m++)
#pragma unroll
        for (int j = 0; j < 4; j++) {
            int row = m * 16 + kg * 4 + j;
            float sum = 0.f;
#pragma unroll
            for (int ww = 0; ww < 8; ww++) sum += red[1][row][ww];
            float inv = 1.0f / sum;
#pragma unroll
            for (int nt = 0; nt < 4; nt++) {
                float p = acc[m][nt][j] * inv;
                __builtin_nontemporal_store(p, &dst[(size_t)row * LK + nt * 16 + r16]);
                P[row][w * 64 + nt * 16 + r16] = f2bf(p);
            }
        }
    __syncthreads();

    int wd = (w & 3) * 16;
    int kh = (w >> 2) * 256;
    const u16* vbase = vT + (size_t)bh * (HD_ * LK);
    f32x4 po[2] = {};
#pragma unroll
    for (int kt = 0; kt < 8; kt++) {
        int k0 = kh + kt * 32;
        bf16x8 bvf = *(const bf16x8*)&vbase[(size_t)(wd + r16) * LK + k0 + kg * 8];
#pragma unroll
        for (int m = 0; m < 2; m++) {
            bf16x8 af = *(const bf16x8*)&P[m * 16 + r16][k0 + kg * 8];
            po[m] = __builtin_amdgcn_mfma_f32_16x16x32_bf16(af, bvf, po[m], 0, 0, 0);
        }
    }
    if (w >= 4) {
#pragma unroll
        for (int m = 0; m < 2; m++)
#pragma unroll
            for (int j = 0; j < 4; j++)
                pred[w & 3][m * 16 + kg * 4 + j][r16] = po[m][j];
    }
    __syncthreads();
    if (w < 4) {
#pragma unroll
        for (int m = 0; m < 2; m++)
#pragma unroll
            for (int j = 0; j < 4; j++) {
                int row = m * 16 + kg * 4 + j;
                float v = po[m][j] + pred[w][row][r16];
                ctx[((size_t)(b * LQ + q0 + row)) * HDIM + h * HD_ + wd + r16] = f2bf(v);
            }
    }
}

// ---- K4: output projection (bf16 gemm_bt, m97 structure, f32 out) ----
__global__ __launch_bounds__(256) void oproj2_kernel(
    const u16* __restrict__ ctx, const u16* __restrict__ WT,
    const float* __restrict__ bias, float* __restrict__ out)
{
    __shared__ u16 As[128 * 64];
    __shared__ u16 Bs[128 * 64];
    int bid = blockIdx.x;
    int idx = (bid & 7) * 32 + (bid >> 3);
    int Mb = (idx >> 3) * 128, Nb = (idx & 7) * 128;
    int tid = threadIdx.x, lane = tid & 63, w = tid >> 6;
    int wm = (w & 1) * 64, wn = (w >> 1) * 64;
    int r16 = lane & 15, kg = lane >> 4;
    int rsw = (r16 & 7) * 8;
    int srow = lane >> 3;
    int scol = 8 * ((lane & 7) ^ (lane >> 3));
    const u16* gA = ctx + (size_t)Mb * HDIM;
    const u16* gB = WT + (size_t)Nb * HDIM;

    f32x4 acc[4][4] = {};
    for (int k0 = 0; k0 < HDIM; k0 += 64) {
#pragma unroll
        for (int i = 0; i < 4; i++) {
            int c = w * 4 + i;
            int row = c * 8 + srow;
            gload_lds16(&gA[(size_t)row * HDIM + k0 + scol], &As[c * 512]);
            gload_lds16(&gB[(size_t)row * HDIM + k0 + scol], &Bs[c * 512]);
        }
        __syncthreads();
#pragma unroll
        for (int kk = 0; kk < 2; kk++) {
            int colp = (kk * 32 + kg * 8) ^ rsw;
            bf16x8 a[4], b[4];
#pragma unroll
            for (int mt = 0; mt < 4; mt++) a[mt] = *(const bf16x8*)&As[(wm + mt * 16 + r16) * 64 + colp];
#pragma unroll
            for (int nt = 0; nt < 4; nt++) b[nt] = *(const bf16x8*)&Bs[(wn + nt * 16 + r16) * 64 + colp];
#pragma unroll
            for (int mt = 0; mt < 4; mt++)
#pragma unroll
                for (int nt = 0; nt < 4; nt++)
                    acc[mt][nt] = __builtin_amdgcn_mfma_f32_16x16x32_bf16(a[mt], b[nt], acc[mt][nt], 0, 0, 0);
        }
        __syncthreads();
    }
    int cr = (lane >> 4) * 4, cc = lane & 15;
#pragma unroll
    for (int nt = 0; nt < 4; nt++) {
        int n = Nb + wn + nt * 16 + cc;
        float bv = bias[n];
#pragma unroll
        for (int mt = 0; mt < 4; mt++) {
#pragma unroll
            for (int j = 0; j < 4; j++) {
                int m = Mb + wm + mt * 16 + cr + j;
                out[(size_t)m * HDIM + n] = acc[mt][nt][j] + bv;
            }
        }
    }
}

extern "C" void kernel_launch(void* const* d_in, const int* in_sizes, int n_in,
                              void* d_out, int out_size, void* d_ws, size_t ws_size,
                              hipStream_t stream) {
    (void)in_sizes; (void)n_in; (void)out_size; (void)ws_size;
    const float* query = (const float*)d_in[0];
    const float* key_  = (const float*)d_in[1];
    const float* value = (const float*)d_in[2];
    const int*   kpm   = (const int*)d_in[3];
    const float* Wq = (const float*)d_in[4];  const float* bq = (const float*)d_in[5];
    const float* Wk = (const float*)d_in[6];  const float* bk = (const float*)d_in[7];
    const float* Wv = (const float*)d_in[8];  const float* bv = (const float*)d_in[9];
    const float* Wo = (const float*)d_in[10]; const float* bo = (const float*)d_in[11];
    const float* rel_table  = (const float*)d_in[12];
    const float* local_bias = (const float*)d_in[13];
    const float* log_scale  = (const float*)d_in[14];
    const float* att_bias   = (const float*)d_in[15];

    char* ws = (char*)d_ws;
    u16* WTq = (u16*)(ws + 0ull);
    u16* WTk = (u16*)(ws + (2ull << 20));
    u16* WTv = (u16*)(ws + (4ull << 20));
    u16* WTo = (u16*)(ws + (6ull << 20));
    u16* qb  = (u16*)(ws + (8ull << 20));
    u16* kb  = (u16*)(ws + (16ull << 20));
    u16* vb  = (u16*)(ws + (24ull << 20));
    u16* xq  = (u16*)(ws + (32ull << 20));   // dead after proj2
    u16* vT  = (u16*)(ws + (32ull << 20));   // aliases xq; vtrans (mid) runs after proj2
    u16* xk  = (u16*)(ws + (40ull << 20));   // dead after proj2
    u16* ctx = (u16*)(ws + (40ull << 20));   // aliases xk
    u16* xv  = (u16*)(ws + (48ull << 20));   // dead after proj2
    u16* Tb  = (u16*)(ws + (48ull << 20));   // aliases xv; biasprep (mid) runs after proj2

    float* out  = (float*)d_out;
    float* attn = out + (size_t)4096 * 1024;

    prep1_kernel<<<16384, 256, 0, stream>>>(query, key_, value, xq, xk, xv,
                                            Wq, Wk, Wv, Wo, WTq, WTk, WTv, WTo);
    proj2_kernel<<<768, 256, 0, stream>>>(xq, xk, xv, WTq, WTk, WTv, bq, bk, bv, qb, kb, vb);
    mid_kernel<<<6144, 256, 0, stream>>>(vb, vT, rel_table, local_bias, log_scale, att_bias, Tb);
    attn2_kernel<<<dim3(16, 128), 512, 0, stream>>>(qb, kb, vT, kpm, Tb, log_scale, attn, ctx);
    oproj2_kernel<<<256, 256, 0, stream>>>(ctx, WTo, bo, out);
}